// Round 2
// 214.177 us; speedup vs baseline: 1.0151x; 1.0151x over previous
//
#include <hip/hip_runtime.h>

typedef unsigned short ushort_t;
typedef __attribute__((ext_vector_type(8))) short short8;
typedef __attribute__((ext_vector_type(4))) float floatx4;

#define G_   129
#define F_   96
#define O_   96
#define T_   512
#define KD   288    // K*F, kd = kk*96 + f
#define LDB  296    // Wl padded row stride (288 + 8)
#define SROW 40     // x-slab row stride in ushorts (80 B) -> bank-conflict-free
#define SLAB (36 * SROW)   // per-wave slab: 36 rows (34 used) = 2880 B

// f32 -> bf16 RNE (finite inputs)
__device__ __forceinline__ unsigned f2bf(float f) {
    unsigned u = __builtin_bit_cast(unsigned, f);
    u += 0x7FFFu + ((u >> 16) & 1u);
    return u >> 16;
}
// packed pair f32x2 -> bf16x2 in one dword (integer pack; no class types)
__device__ __forceinline__ unsigned pk2(float a, float b) {
    return f2bf(a) | (f2bf(b) << 16);
}

// Single fused kernel: weight permute+convert (f32 [G,O,F,K] -> bf16 Wl[o][kk*96+f])
// happens during LDS staging — no wt_permute kernel, no workspace round-trip,
// no inter-kernel serialization. x set-0 loads issue BEFORE weight staging so their
// HBM latency hides under the staging loads + barrier.
__global__ __launch_bounds__(512, 4) void conv_mfma(
    const float* __restrict__ x, const float* __restrict__ w,
    const float* __restrict__ bias, float* __restrict__ out)
{
    __shared__ __align__(16) ushort_t Wl[O_ * LDB];   // 56,832 B
    __shared__ __align__(16) ushort_t Xs[8 * SLAB];   // 23,040 B

    const int g    = blockIdx.y;
    const int m0   = blockIdx.x * 256;
    const int tid  = threadIdx.x;
    const int wave = tid >> 6;
    const int lane = tid & 63;
    const int ln   = lane & 15;
    const int q    = lane >> 4;

    const int m0r = m0 + wave * 32;       // this wave's 32 rows
    const int b   = m0r >> 9;
    const int tb  = m0r & 511;

    // Per-task constants for x-slab staging: 5 insts x 64 lanes; task -> (row, seg).
    // Slab row rr holds global t = tb + rr - 1 (rows 0..33 used).
    const float* tp[5];
    int  laddr[5];
    bool wr[5], vld[5];
    #pragma unroll
    for (int i = 0; i < 5; ++i) {
        int task = i * 64 + lane;
        int row = task >> 3;            // 0..39
        int seg = task & 7;             // 8 segs x 4 floats = 32-f block
        int tl = tb + row - 1;
        wr[i]  = row < 34;
        vld[i] = wr[i] && ((unsigned)tl < (unsigned)T_);
        int tc = tl < 0 ? 0 : (tl > T_ - 1 ? T_ - 1 : tl);
        tp[i] = x + ((size_t)((b * T_ + tc) * G_ + g) * F_ + seg * 4);
        laddr[i] = wave * SLAB + row * SROW + seg * 4;   // ushort index, 8B-aligned
    }

    auto issueX = [&](int fb, floatx4* v) {
        #pragma unroll
        for (int i = 0; i < 5; ++i)
            v[i] = *(const floatx4*)(tp[i] + fb * 32);
    };
    auto writeX = [&](const floatx4* v) {
        #pragma unroll
        for (int i = 0; i < 5; ++i) {
            if (wr[i]) {
                unsigned lo = pk2(v[i][0], v[i][1]);
                unsigned hi = pk2(v[i][2], v[i][3]);
                if (!vld[i]) { lo = 0u; hi = 0u; }
                uint2 d; d.x = lo; d.y = hi;
                *(uint2*)&Xs[laddr[i]] = d;
            }
        }
    };

    floatx4 va[5], vb[5];
    issueX(0, va);   // set-0 x loads in flight across the whole staging phase

    // Fused weight stage: read 12 consecutive f32 of w[g][o] (16B-aligned: 48B/task),
    // floats j=0..11 are (f,kk)=(4u+j/3, j%3). Repack into three uint2 (4 bf16 each)
    // at Wl[o*LDB + kk*96 + 4u]. 2304 tasks, 512 threads -> 4.5/thread.
    {
        const float* wg = w + (size_t)g * (O_ * KD);
        #pragma unroll
        for (int i = 0; i < 5; ++i) {
            int task = i * 512 + tid;
            if (task < 2304) {
                int o = task / 24;
                int u = task - o * 24;
                const float* p = wg + o * KD + u * 12;
                float4 A = *(const float4*)(p);
                float4 B = *(const float4*)(p + 4);
                float4 C = *(const float4*)(p + 8);
                int base = o * LDB + u * 4;
                uint2 d0, d1, d2;
                d0.x = pk2(A.x, A.w);  d0.y = pk2(B.z, C.y);   // kk=0: f=4u..4u+3
                d1.x = pk2(A.y, B.x);  d1.y = pk2(B.w, C.z);   // kk=1
                d2.x = pk2(A.z, B.y);  d2.y = pk2(C.x, C.w);   // kk=2
                *(uint2*)&Wl[base]       = d0;
                *(uint2*)&Wl[base +  96] = d1;
                *(uint2*)&Wl[base + 192] = d2;
            }
        }
    }

    // Hoist bias (removes the epilogue latency bubble)
    float bv[6];
    #pragma unroll
    for (int nt = 0; nt < 6; ++nt) bv[nt] = bias[g * O_ + nt * 16 + ln];

    __syncthreads();   // the only barrier

    floatx4 acc[2][6];
    #pragma unroll
    for (int s = 0; s < 2; ++s)
        #pragma unroll
        for (int nt = 0; nt < 6; ++nt)
            acc[s][nt] = (floatx4){0.f, 0.f, 0.f, 0.f};

    auto compute = [&](int fb) {
        #pragma unroll
        for (int kk = 0; kk < 3; ++kk) {
            const short8 a0 = *(const short8*)&Xs[wave * SLAB + (ln + kk) * SROW + q * 8];
            const short8 a1 = *(const short8*)&Xs[wave * SLAB + (16 + ln + kk) * SROW + q * 8];
            const int c32 = (kk * 3 + fb) * 32;   // Wl column block kd = kk*96 + fb*32
            #pragma unroll
            for (int nt = 0; nt < 6; ++nt) {
                const short8 bbv = *(const short8*)&Wl[(nt * 16 + ln) * LDB + c32 + q * 8];
                acc[0][nt] = __builtin_amdgcn_mfma_f32_16x16x32_bf16(a0, bbv, acc[0][nt], 0, 0, 0);
                acc[1][nt] = __builtin_amdgcn_mfma_f32_16x16x32_bf16(a1, bbv, acc[1][nt], 0, 0, 0);
            }
        }
    };

    // 2-deep pipeline, set-0 already landed during staging+barrier -> no cold stall.
    issueX(1, vb);
    writeX(va);        // set 0
    compute(0);
    issueX(2, va);
    writeX(vb);        // set 1 (landed during compute(0))
    compute(1);
    writeX(va);        // set 2 (issued one compute-phase earlier)
    compute(2);

    // Epilogue: D row = q*4 + reg, col = ln; + bias; f32 out.
    #pragma unroll
    for (int s = 0; s < 2; ++s) {
        int mbase = m0 + wave * 32 + s * 16 + q * 4;
        #pragma unroll
        for (int nt = 0; nt < 6; ++nt) {
            int o = nt * 16 + ln;
            #pragma unroll
            for (int r = 0; r < 4; ++r) {
                int m = mbase + r;
                out[(size_t)(m * G_ + g) * O_ + o] = acc[s][nt][r] + bv[nt];
            }
        }
    }
}

extern "C" void kernel_launch(void* const* d_in, const int* in_sizes, int n_in,
                              void* d_out, int out_size, void* d_ws, size_t ws_size,
                              hipStream_t stream) {
    const float* x    = (const float*)d_in[0];
    const float* w    = (const float*)d_in[1];
    const float* bias = (const float*)d_in[2];
    float* out = (float*)d_out;
    dim3 grid(2048 / 256, G_);
    conv_mfma<<<grid, dim3(512), 0, stream>>>(x, w, bias, out);
}